// Round 1
// baseline (5248.055 us; speedup 1.0000x reference)
//
#include <hip/hip_runtime.h>
#include <hip/hip_fp16.h>

typedef __attribute__((ext_vector_type(8))) short short8;
typedef __attribute__((ext_vector_type(4))) float floatx4;

#define DEVFN static __device__ __forceinline__

DEVFN short f2h(float v) { return __half_as_short(__float2half(v)); }

DEVFN void gload16(const void* g, void* l) {
  void* gnc = const_cast<void*>(g);
  __builtin_amdgcn_global_load_lds(
      (__attribute__((address_space(1))) void*)gnc,
      (__attribute__((address_space(3))) void*)l, 16, 0, 0);
}

// Fused step kernel.
// MODE 0: z = A @ Wcat^T (+bias) -> LSTM cell -> h writes (d1/d2/d3) + next-x embed copy.
//   A: [1024][ktot] fp16 (swizzled layout), W: [4*1024][ktot] fp16 (swizzled, gate-major)
//   grid (32, 8): blockIdx.x = unit tile (32 units), blockIdx.y = batch tile (128 rows)
// MODE 1: plain GEMM + bias -> f32 out (the fc projection).
//   grid (2, 376): blockIdx.x = 128-col tile, blockIdx.y = 128-row tile. W "gate" stride 32.
template <int MODE>
__global__ __launch_bounds__(256) void step_kernel(
    const short* __restrict__ A, int astride, int ktot,
    const short* __restrict__ W,
    const float* __restrict__ bias,
    float* __restrict__ cbuf,
    short* __restrict__ d1, int s1, int o1,
    short* __restrict__ d2, int s2, int o2,
    short* __restrict__ d3, int s3, int o3,
    short* __restrict__ xdst, int xstride,
    const short* __restrict__ xemb,
    const int* __restrict__ toks,
    float* __restrict__ outp) {
  __shared__ short smem[32768];  // 2 buffers x (A 128x64 | B 4x32x64) fp16
  const int tid = threadIdx.x;
  const int lane = tid & 63;
  const int wv = tid >> 6;
  const int wm = wv >> 1;
  const int wu = wv & 1;
  const int l15 = lane & 15;
  const int l4 = lane >> 4;
  constexpr int GS = (MODE == 0) ? 1024 : 32;
  const int u0 = blockIdx.x * ((MODE == 0) ? 32 : 128);
  const int m0 = blockIdx.y * 128;

  floatx4 acc[4][4];
#pragma unroll
  for (int g = 0; g < 4; ++g)
#pragma unroll
    for (int mi = 0; mi < 4; ++mi) acc[g][mi] = (floatx4){0.f, 0.f, 0.f, 0.f};

  const char* Ab = (const char*)A;
  const char* Wb = (const char*)W;
  const long abytes = (long)astride * 2;
  const long wbytes = (long)ktot * 2;
  const int srow = lane >> 3;
  const int sseg = (lane & 7) * 16;
  const int nkb = ktot >> 6;

  auto stage = [&](int kb, int bufi) {
    const long kboff = (long)kb * 128;
    short* sb = smem + bufi * 16384;
#pragma unroll
    for (int ci = 0; ci < 8; ++ci) {
      const int c = wv * 8 + ci;
      void* lds = (void*)(sb + c * 512);
      if (c < 16) {  // A chunks: rows c*8..c*8+8
        const int row = c * 8 + srow;
        gload16(Ab + (long)(m0 + row) * abytes + kboff + sseg, lds);
      } else {  // B chunks: 4 gates x 32 rows
        const int cb = c - 16;
        const int wrow = (cb >> 2) * GS + u0 + (cb & 3) * 8 + srow;
        gload16(Wb + (long)wrow * wbytes + kboff + sseg, lds);
      }
    }
  };

  stage(0, 0);
  __syncthreads();
  int buf = 0;
  for (int kb = 0; kb < nkb; ++kb) {
    if (kb + 1 < nkb) stage(kb + 1, buf ^ 1);  // prefetch in flight under compute
    const short* sb = smem + buf * 16384;
#pragma unroll
    for (int k0 = 0; k0 < 64; k0 += 32) {
      short8 fa[4];
      short8 fb[4];
#pragma unroll
      for (int mi = 0; mi < 4; ++mi) {
        const int r = wm * 64 + mi * 16 + l15;
        fa[mi] = *(const short8*)(sb + r * 64 + ((k0 + l4 * 8) ^ ((r & 7) << 3)));
      }
      {
        const int r = wu * 16 + l15;
        const int kk = (k0 + l4 * 8) ^ ((r & 7) << 3);
#pragma unroll
        for (int g = 0; g < 4; ++g)
          fb[g] = *(const short8*)(sb + 8192 + (g * 32 + r) * 64 + kk);
      }
#pragma unroll
      for (int g = 0; g < 4; ++g)
#pragma unroll
        for (int mi = 0; mi < 4; ++mi)
          asm volatile("v_mfma_f32_16x16x32_f16 %0, %1, %2, %0"
                       : "+v"(acc[g][mi])
                       : "v"(fa[mi]), "v"(fb[g]));
    }
    __syncthreads();  // drains prefetch vmcnt + protects LDS WAR
    buf ^= 1;
  }
  asm volatile("s_nop 7\ns_nop 7\ns_nop 7");  // MFMA -> VALU read hazard guard

  if constexpr (MODE == 0) {
    const int u = u0 + wu * 16 + l15;
    const float bi = bias[u];
    const float bff = bias[1024 + u];
    const float bg = bias[2048 + u];
    const float bo = bias[3072 + u];
#pragma unroll
    for (int mi = 0; mi < 4; ++mi) {
#pragma unroll
      for (int j = 0; j < 4; ++j) {
        const int r = m0 + wm * 64 + mi * 16 + l4 * 4 + j;
        const float zi = acc[0][mi][j] + bi;
        const float zf = acc[1][mi][j] + bff;
        const float zg = acc[2][mi][j] + bg;
        const float zo = acc[3][mi][j] + bo;
        const float gi = 1.f / (1.f + expf(-zi));
        const float gf = 1.f / (1.f + expf(-zf));
        const float gg = tanhf(zg);
        const float go = 1.f / (1.f + expf(-zo));
        const long cix = (long)r * 1024 + u;
        const float cn = gf * cbuf[cix] + gi * gg;
        cbuf[cix] = cn;
        const short hb = f2h(go * tanhf(cn));
        const int usw = u ^ ((r & 7) << 3);
        if (d1) d1[(long)r * s1 + o1 + usw] = hb;
        if (d2) d2[(long)r * s2 + o2 + usw] = hb;
        if (d3) d3[(long)r * s3 + o3 + usw] = hb;
      }
    }
    // next-step embedding gather (only unit-tile-0 blocks; writes next slot -> no race)
    if (xdst && blockIdx.x == 0) {
      for (int i = tid; i < 4096; i += 256) {
        const int row = i >> 5;
        const int e8 = (i & 31) * 8;
        const int b = m0 + row;
        const int tok = toks[b];
        const short8 v = *(const short8*)(xemb + (long)tok * 256 + e8);
        *(short8*)(xdst + (long)b * xstride + (e8 ^ ((b & 7) << 3))) = v;
      }
    }
  } else {
#pragma unroll
    for (int g = 0; g < 4; ++g) {
      const int n = u0 + g * 32 + wu * 16 + l15;
      const float bb = bias[n];
#pragma unroll
      for (int mi = 0; mi < 4; ++mi) {
#pragma unroll
        for (int j = 0; j < 4; ++j) {
          const int r = m0 + wm * 64 + mi * 16 + l4 * 4 + j;
          outp[(long)r * 256 + n] = acc[g][mi][j] + bb;
        }
      }
    }
  }
}

// weights -> fp16, [Wih | Whh] concat along K, gate-major rows, K-swizzled
__global__ void wprep(const float* __restrict__ A, const float* __restrict__ B,
                      short* __restrict__ dst, int N, int Ka, int Kb) {
  const int ktot = Ka + Kb;
  const int n8 = ktot >> 3;
  const int total = N * n8;
  for (int idx = blockIdx.x * 256 + threadIdx.x; idx < total; idx += gridDim.x * 256) {
    const int n = idx / n8;
    const int k = (idx - n * n8) * 8;
    const float* s = (k < Ka) ? (A + (long)n * Ka + k) : (B + (long)n * Kb + (k - Ka));
    short8 v;
#pragma unroll
    for (int j = 0; j < 8; ++j) v[j] = f2h(s[j]);
    *(short8*)(dst + (long)n * ktot + (k ^ ((n & 7) << 3))) = v;
  }
}

__global__ void embprep(const float* __restrict__ s, short* __restrict__ d, int total8) {
  const int idx = blockIdx.x * 256 + threadIdx.x;
  if (idx >= total8) return;
  short8 v;
#pragma unroll
  for (int j = 0; j < 8; ++j) v[j] = f2h(s[idx * 8 + j]);
  *(short8*)(d + idx * 8) = v;
}

// fc_W [1024][256] -> fcWt [256][1024] fp16, swizzled
__global__ void fcwprep(const float* __restrict__ fcW, short* __restrict__ dst) {
  const int idx = blockIdx.x * 256 + threadIdx.x;  // 32768
  const int v = idx & 255;
  const int h = (idx >> 8) * 8;
  short8 o;
#pragma unroll
  for (int j = 0; j < 8; ++j) o[j] = f2h(fcW[(long)(h + j) * 256 + v]);
  *(short8*)(dst + (long)v * 1024 + (h ^ ((v & 7) << 3))) = o;
}

// xh_e0 slot0: x = enc_emb[src[0]], h = 0 ; xh_e1 slot0 second half = 0
__global__ void initk(const int* __restrict__ src, const float* __restrict__ emb,
                      short* __restrict__ xe0, short* __restrict__ xe1) {
  const int idx = blockIdx.x * 256 + threadIdx.x;
  if (idx < 1024 * 160) {
    const int b = idx / 160;
    const int k = (idx - b * 160) * 8;
    short8 v;
    if (k < 256) {
      const int tok = src[b];
#pragma unroll
      for (int j = 0; j < 8; ++j) v[j] = f2h(emb[(long)tok * 256 + k + j]);
    } else {
#pragma unroll
      for (int j = 0; j < 8; ++j) v[j] = 0;
    }
    *(short8*)(xe0 + (long)b * 1280 + (k ^ ((b & 7) << 3))) = v;
  } else {
    const int i = idx - 1024 * 160;
    if (i < 1024 * 128) {
      const int b = i >> 7;
      const int k = 1024 + (i & 127) * 8;
      short8 v;
#pragma unroll
      for (int j = 0; j < 8; ++j) v[j] = 0;
      *(short8*)(xe1 + (long)b * 2048 + (k ^ ((b & 7) << 3))) = v;
    }
  }
}

extern "C" void kernel_launch(void* const* d_in, const int* in_sizes, int n_in,
                              void* d_out, int out_size, void* d_ws, size_t ws_size,
                              hipStream_t stream) {
  (void)in_sizes; (void)n_in; (void)out_size; (void)ws_size;
  const int* src = (const int*)d_in[0];
  const int* tgt = (const int*)d_in[1];
  const float* enc_emb = (const float*)d_in[2];
  const float* eW0i = (const float*)d_in[3];
  const float* eW0h = (const float*)d_in[4];
  const float* eb0 = (const float*)d_in[5];
  const float* eW1i = (const float*)d_in[6];
  const float* eW1h = (const float*)d_in[7];
  const float* eb1 = (const float*)d_in[8];
  const float* dec_emb = (const float*)d_in[9];
  const float* dW0i = (const float*)d_in[10];
  const float* dW0h = (const float*)d_in[11];
  const float* db0 = (const float*)d_in[12];
  const float* dW1i = (const float*)d_in[13];
  const float* dW1h = (const float*)d_in[14];
  const float* db1 = (const float*)d_in[15];
  const float* fcW = (const float*)d_in[16];
  const float* fcb = (const float*)d_in[17];
  float* out = (float*)d_out;

  char* ws = (char*)d_ws;
  size_t off = 0;
  auto carve = [&](size_t bytes) {
    void* p = ws + off;
    off += (bytes + 255) & ~(size_t)255;
    return p;
  };
  short* wc_e0 = (short*)carve(4096l * 1280 * 2);
  short* wc_e1 = (short*)carve(4096l * 2048 * 2);
  short* wc_d0 = (short*)carve(4096l * 1280 * 2);
  short* wc_d1 = (short*)carve(4096l * 2048 * 2);
  short* fcwt = (short*)carve(256l * 1024 * 2);
  short* embe = (short*)carve(256l * 256 * 2);
  short* embd = (short*)carve(256l * 256 * 2);
  short* xe0 = (short*)carve(2l * 1024 * 1280 * 2);
  short* xe1 = (short*)carve(2l * 1024 * 2048 * 2);
  short* xd0 = (short*)carve(2l * 1024 * 1280 * 2);
  short* xd1 = (short*)carve(2l * 1024 * 2048 * 2);
  float* c0 = (float*)carve(1024l * 1024 * 4);
  float* c1 = (float*)carve(1024l * 1024 * 4);
  short* dh1 = (short*)carve(47l * 1024 * 1024 * 2);

  hipMemsetAsync(c0, 0, 1024l * 1024 * 4, stream);
  hipMemsetAsync(c1, 0, 1024l * 1024 * 4, stream);
  hipMemsetAsync(out, 0, 1024l * 256 * 4, stream);  // outputs[0] stays zeros

  wprep<<<2560, 256, 0, stream>>>(eW0i, eW0h, wc_e0, 4096, 256, 1024);
  wprep<<<4096, 256, 0, stream>>>(eW1i, eW1h, wc_e1, 4096, 1024, 1024);
  wprep<<<2560, 256, 0, stream>>>(dW0i, dW0h, wc_d0, 4096, 256, 1024);
  wprep<<<4096, 256, 0, stream>>>(dW1i, dW1h, wc_d1, 4096, 1024, 1024);
  embprep<<<32, 256, 0, stream>>>(enc_emb, embe, 8192);
  embprep<<<32, 256, 0, stream>>>(dec_emb, embd, 8192);
  fcwprep<<<128, 256, 0, stream>>>(fcW, fcwt);
  initk<<<1152, 256, 0, stream>>>(src, enc_emb, xe0, xe1);

  const dim3 cgrid(32, 8);
  const long SL0 = 1024l * 1280;
  const long SL1 = 1024l * 2048;

  // ---- encoder: 32 steps x 2 layers ----
  for (int t = 0; t < 32; ++t) {
    const int cur = t & 1, nxt = (t + 1) & 1;
    short* d1;
    short* xq;
    const short* xemb;
    const int* tk;
    if (t < 31) {
      d1 = xe0 + nxt * SL0; xq = d1; xemb = embe; tk = src + (t + 1) * 1024;
    } else {  // hand off h0/c0 + first decoder token into decoder layer-0 buffer
      d1 = xd0; xq = xd0; xemb = embd; tk = tgt;
    }
    step_kernel<0><<<cgrid, 256, 0, stream>>>(
        xe0 + cur * SL0, 1280, 1280, wc_e0, eb0, c0,
        d1, 1280, 256,
        xe1 + cur * SL1, 2048, 0,  // hs0[t] -> layer1 input (first half, slot cur)
        nullptr, 0, 0,
        xq, 1280, xemb, tk, nullptr);
    short* e1d1 = (t < 31) ? (xe1 + nxt * SL1) : xd1;  // h1 -> next slot / decoder xd1[0]
    step_kernel<0><<<cgrid, 256, 0, stream>>>(
        xe1 + cur * SL1, 2048, 2048, wc_e1, eb1, c1,
        e1d1, 2048, 1024,
        nullptr, 0, 0,
        nullptr, 0, 0,
        nullptr, 0, nullptr, nullptr, nullptr);
  }
  // ---- decoder: 47 steps x 2 layers, h1 archived for batched fc ----
  for (int t = 0; t < 47; ++t) {
    const int cur = t & 1, nxt = (t + 1) & 1;
    step_kernel<0><<<cgrid, 256, 0, stream>>>(
        xd0 + cur * SL0, 1280, 1280, wc_d0, db0, c0,
        xd0 + nxt * SL0, 1280, 256,
        xd1 + cur * SL1, 2048, 0,  // dh0 -> layer1 input (first half, slot cur)
        nullptr, 0, 0,
        xd0 + nxt * SL0, 1280, embd, tgt + (t + 1) * 1024, nullptr);
    step_kernel<0><<<cgrid, 256, 0, stream>>>(
        xd1 + cur * SL1, 2048, 2048, wc_d1, db1, c1,
        xd1 + nxt * SL1, 2048, 1024,
        nullptr, 0, 0,
        dh1 + (long)t * 1024 * 1024, 1024, 0,  // archive dh1[t]
        nullptr, 0, nullptr, nullptr, nullptr);
  }
  // ---- batched fc: out[1:] = dh1_all @ fcWt^T + fc_b ----
  step_kernel<1><<<dim3(2, 376), 256, 0, stream>>>(
      dh1, 1024, 1024, fcwt, fcb, nullptr,
      nullptr, 0, 0, nullptr, 0, 0, nullptr, 0, 0,
      nullptr, 0, nullptr, nullptr, out + 1024l * 256);
}

// Round 2
// 4956.381 us; speedup vs baseline: 1.0588x; 1.0588x over previous
//
#include <hip/hip_runtime.h>
#include <hip/hip_fp16.h>

typedef __attribute__((ext_vector_type(8))) short short8;
typedef __attribute__((ext_vector_type(4))) float floatx4;

#define DEVFN static __device__ __forceinline__

DEVFN short f2h(float v) { return __half_as_short(__float2half(v)); }

DEVFN void gload16(const void* g, void* l) {
  void* gnc = const_cast<void*>(g);
  __builtin_amdgcn_global_load_lds(
      (__attribute__((address_space(1))) void*)gnc,
      (__attribute__((address_space(3))) void*)l, 16, 0, 0);
}

// Fused step kernel.
// MODE 0: z = A @ Wcat^T (+bias) -> LSTM cell -> h writes (d1/d2/d3) + next-x embed copy.
//   A: [1024][ktot] fp16 LINEAR, W: [4*1024][ktot] fp16 LINEAR (gate-major rows)
//   LDS layout is XOR-swizzled; the swizzle is applied on the global SOURCE
//   address of global_load_lds (16B-granular) and on the ds_read offset.
//   grid (32, 8): blockIdx.x = unit tile (32 units), blockIdx.y = batch tile (128 rows)
// MODE 1: plain GEMM + bias -> f32 out (the fc projection).
//   grid (2, 376): blockIdx.x = 128-col tile, blockIdx.y = 128-row tile. W "gate" stride 32.
template <int MODE>
__global__ __launch_bounds__(256) void step_kernel(
    const short* __restrict__ A, int astride, int ktot,
    const short* __restrict__ W,
    const float* __restrict__ bias,
    float* __restrict__ cbuf,
    short* __restrict__ d1, int s1, int o1,
    short* __restrict__ d2, int s2, int o2,
    short* __restrict__ d3, int s3, int o3,
    short* __restrict__ xdst, int xstride,
    const short* __restrict__ xemb,
    const int* __restrict__ toks,
    float* __restrict__ outp) {
  __shared__ short smem[49152];  // 3 buffers x (A 128x64 | B 128x64) fp16 = 96 KB
  const int tid = threadIdx.x;
  const int lane = tid & 63;
  const int wv = tid >> 6;
  const int wm = wv >> 1;
  const int wu = wv & 1;
  const int l15 = lane & 15;
  const int l4 = lane >> 4;
  constexpr int GS = (MODE == 0) ? 1024 : 32;
  const int u0 = blockIdx.x * ((MODE == 0) ? 32 : 128);
  const int m0 = blockIdx.y * 128;

  floatx4 acc[4][4];
#pragma unroll
  for (int g = 0; g < 4; ++g)
#pragma unroll
    for (int mi = 0; mi < 4; ++mi) acc[g][mi] = (floatx4){0.f, 0.f, 0.f, 0.f};

  const char* Ab = (const char*)A;
  const char* Wb = (const char*)W;
  const long abytes = (long)astride * 2;
  const long wbytes = (long)ktot * 2;
  const int srow = lane >> 3;              // 0..7 : row within 8-row chunk
  const int sseg = (lane & 7) * 16;        // byte seg within 128B row-slice
  const int swseg = sseg ^ (srow << 4);    // source-side swizzle (matches ds_read XOR)
  const int nkb = ktot >> 6;

  auto stage = [&](int kb, int bufi) {
    const long kboff = (long)kb * 128;
    short* sb = smem + bufi * 16384;
#pragma unroll
    for (int ci = 0; ci < 8; ++ci) {
      const int c = wv * 8 + ci;
      void* lds = (void*)(sb + c * 512);
      if (c < 16) {  // A chunks: rows c*8..c*8+8
        const int row = c * 8 + srow;
        gload16(Ab + (long)(m0 + row) * abytes + kboff + swseg, lds);
      } else {  // B chunks: 4 gates x 32 rows
        const int cb = c - 16;
        const int wrow = (cb >> 2) * GS + u0 + (cb & 3) * 8 + srow;
        gload16(Wb + (long)wrow * wbytes + kboff + swseg, lds);
      }
    }
  };

  // 3-buffer pipeline, prefetch depth 2, counted vmcnt (never drain mid-loop).
  stage(0, 0);
  stage(1, 1);
  int b0 = 0, b1 = 1, b2 = 2;
  for (int kb = 0; kb < nkb; ++kb) {
    if (kb + 1 < nkb) {
      asm volatile("s_waitcnt vmcnt(8)" ::: "memory");  // tile kb landed; kb+1 in flight
    } else {
      asm volatile("s_waitcnt vmcnt(0)" ::: "memory");  // final drain
    }
    __builtin_amdgcn_s_barrier();
    if (kb + 2 < nkb) stage(kb + 2, b2);  // safe: reads of kb-1 (same buf) done pre-barrier
    const short* sb = smem + b0 * 16384;
    __builtin_amdgcn_s_setprio(1);
#pragma unroll
    for (int k0 = 0; k0 < 64; k0 += 32) {
      short8 fa[4];
      short8 fb[4];
#pragma unroll
      for (int mi = 0; mi < 4; ++mi) {
        const int r = wm * 64 + mi * 16 + l15;
        fa[mi] = *(const short8*)(sb + r * 64 + ((k0 + l4 * 8) ^ ((r & 7) << 3)));
      }
      {
        const int r = wu * 16 + l15;
        const int kk = (k0 + l4 * 8) ^ ((r & 7) << 3);
#pragma unroll
        for (int g = 0; g < 4; ++g)
          fb[g] = *(const short8*)(sb + 8192 + (g * 32 + r) * 64 + kk);
      }
#pragma unroll
      for (int g = 0; g < 4; ++g)
#pragma unroll
        for (int mi = 0; mi < 4; ++mi)
          asm volatile("v_mfma_f32_16x16x32_f16 %0, %1, %2, %0"
                       : "+v"(acc[g][mi])
                       : "v"(fa[mi]), "v"(fb[g]));
    }
    __builtin_amdgcn_s_setprio(0);
    const int t = b0; b0 = b1; b1 = b2; b2 = t;
  }
  asm volatile("s_nop 7\ns_nop 7\ns_nop 7");  // MFMA -> VALU read hazard guard

  if constexpr (MODE == 0) {
    __syncthreads();  // all LDS reads done; smem reusable for h transpose
    short* ht = smem;  // [128][40] padded fp16 tile (10 KB)
    const int u = u0 + wu * 16 + l15;
    const float bi = bias[u];
    const float bff = bias[1024 + u];
    const float bg = bias[2048 + u];
    const float bo = bias[3072 + u];
    const int uloc = wu * 16 + l15;
#pragma unroll
    for (int mi = 0; mi < 4; ++mi) {
#pragma unroll
      for (int j = 0; j < 4; ++j) {
        const int rl = wm * 64 + mi * 16 + l4 * 4 + j;
        const int r = m0 + rl;
        const float zi = acc[0][mi][j] + bi;
        const float zf = acc[1][mi][j] + bff;
        const float zg = acc[2][mi][j] + bg;
        const float zo = acc[3][mi][j] + bo;
        const float gi = 1.f / (1.f + expf(-zi));
        const float gf = 1.f / (1.f + expf(-zf));
        const float gg = tanhf(zg);
        const float go = 1.f / (1.f + expf(-zo));
        const long cix = (long)r * 1024 + u;
        const float cn = gf * cbuf[cix] + gi * gg;
        cbuf[cix] = cn;
        ht[rl * 40 + uloc] = f2h(go * tanhf(cn));
      }
    }
    __syncthreads();
    // coalesced h writes: thread -> 32B (16 shorts) of one row; 64B/row full sectors
    {
      const int rl = tid >> 1;
      const int half = (tid & 1) * 16;
      const short8 v0 = *(const short8*)(ht + rl * 40 + half);
      const short8 v1 = *(const short8*)(ht + rl * 40 + half + 8);
      const long col = u0 + half;
      if (d1) {
        short* p = d1 + (long)(m0 + rl) * s1 + o1 + col;
        *(short8*)p = v0; *(short8*)(p + 8) = v1;
      }
      if (d2) {
        short* p = d2 + (long)(m0 + rl) * s2 + o2 + col;
        *(short8*)p = v0; *(short8*)(p + 8) = v1;
      }
      if (d3) {
        short* p = d3 + (long)(m0 + rl) * s3 + o3 + col;
        *(short8*)p = v0; *(short8*)(p + 8) = v1;
      }
    }
    // next-step embedding gather (only unit-tile-0 blocks; writes next slot -> no race)
    if (xdst && blockIdx.x == 0) {
      for (int i = tid; i < 4096; i += 256) {
        const int row = i >> 5;
        const int e8 = (i & 31) * 8;
        const int b = m0 + row;
        const int tok = toks[b];
        const short8 v = *(const short8*)(xemb + (long)tok * 256 + e8);
        *(short8*)(xdst + (long)b * xstride + e8) = v;
      }
    }
  } else {
#pragma unroll
    for (int g = 0; g < 4; ++g) {
      const int n = u0 + g * 32 + wu * 16 + l15;
      const float bb = bias[n];
#pragma unroll
      for (int mi = 0; mi < 4; ++mi) {
#pragma unroll
        for (int j = 0; j < 4; ++j) {
          const int r = m0 + wm * 64 + mi * 16 + l4 * 4 + j;
          outp[(long)r * 256 + n] = acc[g][mi][j] + bb;
        }
      }
    }
  }
}

// weights -> fp16, [Wih | Whh] concat along K, gate-major rows, LINEAR layout
__global__ void wprep(const float* __restrict__ A, const float* __restrict__ B,
                      short* __restrict__ dst, int N, int Ka, int Kb) {
  const int ktot = Ka + Kb;
  const int n8 = ktot >> 3;
  const int total = N * n8;
  for (int idx = blockIdx.x * 256 + threadIdx.x; idx < total; idx += gridDim.x * 256) {
    const int n = idx / n8;
    const int k = (idx - n * n8) * 8;
    const float* s = (k < Ka) ? (A + (long)n * Ka + k) : (B + (long)n * Kb + (k - Ka));
    short8 v;
#pragma unroll
    for (int j = 0; j < 8; ++j) v[j] = f2h(s[j]);
    *(short8*)(dst + (long)n * ktot + k) = v;
  }
}

__global__ void embprep(const float* __restrict__ s, short* __restrict__ d, int total8) {
  const int idx = blockIdx.x * 256 + threadIdx.x;
  if (idx >= total8) return;
  short8 v;
#pragma unroll
  for (int j = 0; j < 8; ++j) v[j] = f2h(s[idx * 8 + j]);
  *(short8*)(d + idx * 8) = v;
}

// fc_W [1024][256] -> fcWt [256][1024] fp16, LINEAR
__global__ void fcwprep(const float* __restrict__ fcW, short* __restrict__ dst) {
  const int idx = blockIdx.x * 256 + threadIdx.x;  // 32768
  const int v = idx & 255;
  const int h = (idx >> 8) * 8;
  short8 o;
#pragma unroll
  for (int j = 0; j < 8; ++j) o[j] = f2h(fcW[(long)(h + j) * 256 + v]);
  *(short8*)(dst + (long)v * 1024 + h) = o;
}

// xh_e0 slot0: x = enc_emb[src[0]], h = 0 ; xh_e1 slot0 second half = 0   (LINEAR)
__global__ void initk(const int* __restrict__ src, const float* __restrict__ emb,
                      short* __restrict__ xe0, short* __restrict__ xe1) {
  const int idx = blockIdx.x * 256 + threadIdx.x;
  if (idx < 1024 * 160) {
    const int b = idx / 160;
    const int k = (idx - b * 160) * 8;
    short8 v;
    if (k < 256) {
      const int tok = src[b];
#pragma unroll
      for (int j = 0; j < 8; ++j) v[j] = f2h(emb[(long)tok * 256 + k + j]);
    } else {
#pragma unroll
      for (int j = 0; j < 8; ++j) v[j] = 0;
    }
    *(short8*)(xe0 + (long)b * 1280 + k) = v;
  } else {
    const int i = idx - 1024 * 160;
    if (i < 1024 * 128) {
      const int b = i >> 7;
      const int k = 1024 + (i & 127) * 8;
      short8 v;
#pragma unroll
      for (int j = 0; j < 8; ++j) v[j] = 0;
      *(short8*)(xe1 + (long)b * 2048 + k) = v;
    }
  }
}

extern "C" void kernel_launch(void* const* d_in, const int* in_sizes, int n_in,
                              void* d_out, int out_size, void* d_ws, size_t ws_size,
                              hipStream_t stream) {
  (void)in_sizes; (void)n_in; (void)out_size; (void)ws_size;
  const int* src = (const int*)d_in[0];
  const int* tgt = (const int*)d_in[1];
  const float* enc_emb = (const float*)d_in[2];
  const float* eW0i = (const float*)d_in[3];
  const float* eW0h = (const float*)d_in[4];
  const float* eb0 = (const float*)d_in[5];
  const float* eW1i = (const float*)d_in[6];
  const float* eW1h = (const float*)d_in[7];
  const float* eb1 = (const float*)d_in[8];
  const float* dec_emb = (const float*)d_in[9];
  const float* dW0i = (const float*)d_in[10];
  const float* dW0h = (const float*)d_in[11];
  const float* db0 = (const float*)d_in[12];
  const float* dW1i = (const float*)d_in[13];
  const float* dW1h = (const float*)d_in[14];
  const float* db1 = (const float*)d_in[15];
  const float* fcW = (const float*)d_in[16];
  const float* fcb = (const float*)d_in[17];
  float* out = (float*)d_out;

  char* ws = (char*)d_ws;
  size_t off = 0;
  auto carve = [&](size_t bytes) {
    void* p = ws + off;
    off += (bytes + 255) & ~(size_t)255;
    return p;
  };
  short* wc_e0 = (short*)carve(4096l * 1280 * 2);
  short* wc_e1 = (short*)carve(4096l * 2048 * 2);
  short* wc_d0 = (short*)carve(4096l * 1280 * 2);
  short* wc_d1 = (short*)carve(4096l * 2048 * 2);
  short* fcwt = (short*)carve(256l * 1024 * 2);
  short* embe = (short*)carve(256l * 256 * 2);
  short* embd = (short*)carve(256l * 256 * 2);
  short* xe0 = (short*)carve(2l * 1024 * 1280 * 2);
  short* xe1 = (short*)carve(2l * 1024 * 2048 * 2);
  short* xd0 = (short*)carve(2l * 1024 * 1280 * 2);
  short* xd1 = (short*)carve(2l * 1024 * 2048 * 2);
  float* c0 = (float*)carve(1024l * 1024 * 4);
  float* c1 = (float*)carve(1024l * 1024 * 4);
  short* dh1 = (short*)carve(47l * 1024 * 1024 * 2);

  hipMemsetAsync(c0, 0, 1024l * 1024 * 4, stream);
  hipMemsetAsync(c1, 0, 1024l * 1024 * 4, stream);
  hipMemsetAsync(out, 0, 1024l * 256 * 4, stream);  // outputs[0] stays zeros

  wprep<<<2560, 256, 0, stream>>>(eW0i, eW0h, wc_e0, 4096, 256, 1024);
  wprep<<<4096, 256, 0, stream>>>(eW1i, eW1h, wc_e1, 4096, 1024, 1024);
  wprep<<<2560, 256, 0, stream>>>(dW0i, dW0h, wc_d0, 4096, 256, 1024);
  wprep<<<4096, 256, 0, stream>>>(dW1i, dW1h, wc_d1, 4096, 1024, 1024);
  embprep<<<32, 256, 0, stream>>>(enc_emb, embe, 8192);
  embprep<<<32, 256, 0, stream>>>(dec_emb, embd, 8192);
  fcwprep<<<128, 256, 0, stream>>>(fcW, fcwt);
  initk<<<1152, 256, 0, stream>>>(src, enc_emb, xe0, xe1);

  const dim3 cgrid(32, 8);
  const long SL0 = 1024l * 1280;
  const long SL1 = 1024l * 2048;

  // ---- encoder: 32 steps x 2 layers ----
  for (int t = 0; t < 32; ++t) {
    const int cur = t & 1, nxt = (t + 1) & 1;
    short* d1;
    short* xq;
    const short* xemb;
    const int* tk;
    if (t < 31) {
      d1 = xe0 + nxt * SL0; xq = d1; xemb = embe; tk = src + (t + 1) * 1024;
    } else {  // hand off h0/c0 + first decoder token into decoder layer-0 buffer
      d1 = xd0; xq = xd0; xemb = embd; tk = tgt;
    }
    step_kernel<0><<<cgrid, 256, 0, stream>>>(
        xe0 + cur * SL0, 1280, 1280, wc_e0, eb0, c0,
        d1, 1280, 256,
        xe1 + cur * SL1, 2048, 0,  // hs0[t] -> layer1 input (first half, slot cur)
        nullptr, 0, 0,
        xq, 1280, xemb, tk, nullptr);
    short* e1d1 = (t < 31) ? (xe1 + nxt * SL1) : xd1;  // h1 -> next slot / decoder xd1[0]
    step_kernel<0><<<cgrid, 256, 0, stream>>>(
        xe1 + cur * SL1, 2048, 2048, wc_e1, eb1, c1,
        e1d1, 2048, 1024,
        nullptr, 0, 0,
        nullptr, 0, 0,
        nullptr, 0, nullptr, nullptr, nullptr);
  }
  // ---- decoder: 47 steps x 2 layers, h1 archived for batched fc ----
  for (int t = 0; t < 47; ++t) {
    const int cur = t & 1, nxt = (t + 1) & 1;
    step_kernel<0><<<cgrid, 256, 0, stream>>>(
        xd0 + cur * SL0, 1280, 1280, wc_d0, db0, c0,
        xd0 + nxt * SL0, 1280, 256,
        xd1 + cur * SL1, 2048, 0,  // dh0 -> layer1 input (first half, slot cur)
        nullptr, 0, 0,
        xd0 + nxt * SL0, 1280, embd, tgt + (t + 1) * 1024, nullptr);
    step_kernel<0><<<cgrid, 256, 0, stream>>>(
        xd1 + cur * SL1, 2048, 2048, wc_d1, db1, c1,
        xd1 + nxt * SL1, 2048, 1024,
        nullptr, 0, 0,
        dh1 + (long)t * 1024 * 1024, 1024, 0,  // archive dh1[t]
        nullptr, 0, nullptr, nullptr, nullptr);
  }
  // ---- batched fc: out[1:] = dh1_all @ fcWt^T + fc_b ----
  step_kernel<1><<<dim3(2, 376), 256, 0, stream>>>(
      dh1, 1024, 1024, fcwt, fcb, nullptr,
      nullptr, 0, 0, nullptr, 0, 0, nullptr, 0, 0,
      nullptr, 0, nullptr, nullptr, out + 1024l * 256);
}